// Round 3
// baseline (1223.395 us; speedup 1.0000x reference)
//
#include <hip/hip_runtime.h>
#include <hip/hip_bf16.h>
#include <cstdint>
#include <cstddef>

#define DIM 192
#define NSL 11
#define NB 64
#define NN 4096
#define HIDN 128
#define LN_EPS 1e-5f
#define EPS_A 1e-8f
#define SCALE_Q 0.07216878364870323f  // 192^-0.5

// ---------------------------------------------------------------- utilities
__device__ __forceinline__ float wred(float v) {
#pragma unroll
  for (int m = 32; m; m >>= 1) v += __shfl_xor(v, m, 64);
  return v;
}

// ---------------------------------------------------------------- slots init
__global__ void k_init_slots(const float* __restrict__ noise, const float* __restrict__ mu,
                             const float* __restrict__ sig, float* __restrict__ slots) {
  int i = blockIdx.x * 256 + threadIdx.x;
  if (i < NB * NSL * DIM) {
    int d = i % DIM;
    slots[i] = mu[d] + sig[d] * noise[i];
  }
}

// ---------------------------------------------------------------- per-row LN stats of inputs: (rstd, mu*rstd)
// grid 8192 x 256 threads (4 waves); wave handles 8 rows, fully coalesced reads.
__global__ __launch_bounds__(256) void k_stats(const float* __restrict__ x, float2* __restrict__ st) {
  const int tid = threadIdx.x, wave = tid >> 6, lane = tid & 63;
  const int base = blockIdx.x * 32 + wave * 8;
#pragma unroll
  for (int rr = 0; rr < 8; ++rr) {
    const float* rp = x + (size_t)(base + rr) * DIM;
    float a = rp[lane], b = rp[lane + 64], c = rp[lane + 128];
    float s  = wred(a + b + c);
    float ss = wred(a * a + b * b + c * c);
    if (lane == 0) {
      float mu  = s * (1.0f / DIM);
      float var = ss * (1.0f / DIM) - mu * mu;
      float rstd = rsqrtf(var + LN_EPS);
      st[base + rr] = make_float2(rstd, mu * rstd);
    }
  }
}

// ---------------------------------------------------------------- per-iter prep: LN(slots) -> q -> folded query
// qt[k][e] = SCALE * ln_in_w[e] * (q[k] @ Wk^T)[e];  t0[k] = sum_e qt;  cp[k] = SCALE*(q.bk + sum_e ln_in_b[e]*qk[k][e])
__global__ __launch_bounds__(192) void k_prep(
    const float* __restrict__ slots, const float* __restrict__ lnw, const float* __restrict__ lnb,
    const float* __restrict__ Wq, const float* __restrict__ bq,
    const float* __restrict__ Wk, const float* __restrict__ bk,
    const float* __restrict__ xw, const float* __restrict__ xb,
    float* __restrict__ qt, float* __restrict__ t0g, float* __restrict__ cpg) {
  const int b = blockIdx.x, tid = threadIdx.x, wave = tid >> 6, lane = tid & 63;
  __shared__ __align__(16) float sn[NSL][DIM];
  __shared__ __align__(16) float qb[NSL][DIM];
  __shared__ float red[3][NSL][2];

  for (int k = wave; k < NSL; k += 3) {
    const float* rp = slots + (size_t)(b * NSL + k) * DIM;
    float a = rp[lane], c = rp[lane + 64], e = rp[lane + 128];
    float s = wred(a + c + e), ss = wred(a * a + c * c + e * e);
    float mu = s * (1.0f / DIM), var = ss * (1.0f / DIM) - mu * mu;
    float rstd = rsqrtf(var + LN_EPS);
    sn[k][lane]       = (a - mu) * rstd * lnw[lane]       + lnb[lane];
    sn[k][lane + 64]  = (c - mu) * rstd * lnw[lane + 64]  + lnb[lane + 64];
    sn[k][lane + 128] = (e - mu) * rstd * lnw[lane + 128] + lnb[lane + 128];
  }
  __syncthreads();

  const int j = tid;
  float acc[NSL];
  const float bj = bq[j];
#pragma unroll
  for (int k = 0; k < NSL; ++k) acc[k] = bj;
  for (int d = 0; d < DIM; d += 4) {
    float w0 = Wq[(d + 0) * DIM + j], w1 = Wq[(d + 1) * DIM + j];
    float w2 = Wq[(d + 2) * DIM + j], w3 = Wq[(d + 3) * DIM + j];
#pragma unroll
    for (int k = 0; k < NSL; ++k) {
      float4 s4 = *(const float4*)&sn[k][d];
      acc[k] = fmaf(s4.w, w3, fmaf(s4.z, w2, fmaf(s4.y, w1, fmaf(s4.x, w0, acc[k]))));
    }
  }
#pragma unroll
  for (int k = 0; k < NSL; ++k) qb[k][j] = acc[k];
  __syncthreads();

  // qk[k] = Wk row j . q[k]
  float qk[NSL];
#pragma unroll
  for (int k = 0; k < NSL; ++k) qk[k] = 0.f;
  const float* wkr = Wk + (size_t)j * DIM;
  for (int d = 0; d < DIM; d += 4) {
    float4 w4 = *(const float4*)(wkr + d);
#pragma unroll
    for (int k = 0; k < NSL; ++k) {
      float4 q4 = *(const float4*)&qb[k][d];
      qk[k] = fmaf(w4.w, q4.w, fmaf(w4.z, q4.z, fmaf(w4.y, q4.y, fmaf(w4.x, q4.x, qk[k]))));
    }
  }
  const float wj = xw[j], bxj = xb[j], bkj = bk[j];
#pragma unroll
  for (int k = 0; k < NSL; ++k) {
    float qtv = SCALE_Q * wj * qk[k];
    qt[((size_t)b * NSL + k) * DIM + j] = qtv;
    float r1 = wred(qtv);
    float r2 = wred(SCALE_Q * (bxj * qk[k] + qb[k][j] * bkj));
    if (lane == 0) { red[wave][k][0] = r1; red[wave][k][1] = r2; }
  }
  __syncthreads();
  if (tid < NSL) {
    t0g[b * NSL + tid] = red[0][tid][0] + red[1][tid][0] + red[2][tid][0];
    cpg[b * NSL + tid] = red[0][tid][1] + red[1][tid][1] + red[2][tid][1];
  }
}

// ---------------------------------------------------------------- dots + softmax + attn write + S/m1 accumulation
// grid (64,8) x 256 threads; thread owns rows n0, n0+256 of its 512-chunk.
__global__ __launch_bounds__(256) void k_attn(
    const float* __restrict__ x, const float2* __restrict__ st,
    const float* __restrict__ qt, const float* __restrict__ t0g, const float* __restrict__ cpg,
    float* __restrict__ attn_out, float* __restrict__ Sg, float* __restrict__ m1g) {
  __shared__ __align__(16) float qs[NSL][DIM];
  __shared__ float t0s[NSL], cps[NSL];
  __shared__ float red[4][NSL][2];
  const int b = blockIdx.x, ch = blockIdx.y, tid = threadIdx.x;

  for (int t = tid; t < NSL * DIM; t += 256) qs[t / DIM][t % DIM] = qt[(size_t)b * NSL * DIM + t];
  if (tid < NSL) { t0s[tid] = t0g[b * NSL + tid]; cps[tid] = cpg[b * NSL + tid]; }
  __syncthreads();

  float dots[NSL][2];
#pragma unroll
  for (int k = 0; k < NSL; ++k) { dots[k][0] = 0.f; dots[k][1] = 0.f; }

  const int n0 = ch * 512 + tid;
  const float* xb0 = x + ((size_t)b * NN + n0) * DIM;
  for (int d = 0; d < DIM; d += 4) {
    float4 x0 = *(const float4*)(xb0 + d);
    float4 x1 = *(const float4*)(xb0 + (size_t)256 * DIM + d);
#pragma unroll
    for (int k = 0; k < NSL; ++k) {
      float4 q4 = *(const float4*)&qs[k][d];
      dots[k][0] = fmaf(x0.w, q4.w, fmaf(x0.z, q4.z, fmaf(x0.y, q4.y, fmaf(x0.x, q4.x, dots[k][0]))));
      dots[k][1] = fmaf(x1.w, q4.w, fmaf(x1.z, q4.z, fmaf(x1.y, q4.y, fmaf(x1.x, q4.x, dots[k][1]))));
    }
  }

  float2 stv0 = st[(size_t)b * NN + n0];
  float2 stv1 = st[(size_t)b * NN + n0 + 256];
  float sS[NSL], sM[NSL];
#pragma unroll
  for (int k = 0; k < NSL; ++k) { sS[k] = 0.f; sM[k] = 0.f; }

#pragma unroll
  for (int i = 0; i < 2; ++i) {
    float2 sv = i ? stv1 : stv0;
    float dv[NSL];
#pragma unroll
    for (int k = 0; k < NSL; ++k) dv[k] = sv.x * dots[k][i] - sv.y * t0s[k] + cps[k];
    float mx = dv[0];
#pragma unroll
    for (int k = 1; k < NSL; ++k) mx = fmaxf(mx, dv[k]);
    float es[NSL], ssum = 0.f;
#pragma unroll
    for (int k = 0; k < NSL; ++k) { es[k] = __expf(dv[k] - mx); ssum += es[k]; }
    float inv = 1.0f / ssum;
    int n = n0 + i * 256;
#pragma unroll
    for (int k = 0; k < NSL; ++k) {
      float a = es[k] * inv + EPS_A;
      attn_out[((size_t)b * NSL + k) * NN + n] = a;
      sS[k] += a;
      sM[k] += a * sv.y;
    }
  }

#pragma unroll
  for (int k = 0; k < NSL; ++k) { sS[k] = wred(sS[k]); sM[k] = wred(sM[k]); }
  const int lane = tid & 63, wave = tid >> 6;
  if (lane == 0) {
#pragma unroll
    for (int k = 0; k < NSL; ++k) { red[wave][k][0] = sS[k]; red[wave][k][1] = sM[k]; }
  }
  __syncthreads();
  if (tid < NSL) {
    atomicAdd(&Sg[b * NSL + tid],  red[0][tid][0] + red[1][tid][0] + red[2][tid][0] + red[3][tid][0]);
    atomicAdd(&m1g[b * NSL + tid], red[0][tid][1] + red[1][tid][1] + red[2][tid][1] + red[3][tid][1]);
  }
}

// ---------------------------------------------------------------- P1[k][e] += sum_n attn[k,n]*rstd_n*x[n,e]
// grid (64,8) x 192 threads; thread j owns column e=j; coalesced x loads.
__global__ __launch_bounds__(192) void k_acc(
    const float* __restrict__ attn, const float* __restrict__ x, const float2* __restrict__ st,
    float* __restrict__ P1) {
  __shared__ __align__(16) float at[NSL][512];
  __shared__ float ssr[512];
  const int b = blockIdx.x, ch = blockIdx.y, tid = threadIdx.x;

  for (int t = tid; t < 512; t += 192) ssr[t] = st[(size_t)b * NN + ch * 512 + t].x;
  __syncthreads();
  for (int t = tid; t < NSL * 512; t += 192) {
    int k = t >> 9, nl = t & 511;
    at[k][nl] = attn[((size_t)b * NSL + k) * NN + ch * 512 + nl] * ssr[nl];
  }
  __syncthreads();

  float acc[NSL];
#pragma unroll
  for (int k = 0; k < NSL; ++k) acc[k] = 0.f;

  const float* xb = x + ((size_t)b * NN + ch * 512) * DIM + tid;
  for (int nl = 0; nl < 512; nl += 4) {
    float v0 = xb[(size_t)(nl + 0) * DIM];
    float v1 = xb[(size_t)(nl + 1) * DIM];
    float v2 = xb[(size_t)(nl + 2) * DIM];
    float v3 = xb[(size_t)(nl + 3) * DIM];
#pragma unroll
    for (int k = 0; k < NSL; ++k) {
      float4 a4 = *(const float4*)&at[k][nl];
      acc[k] = fmaf(v3, a4.w, fmaf(v2, a4.z, fmaf(v1, a4.y, fmaf(v0, a4.x, acc[k]))));
    }
  }
#pragma unroll
  for (int k = 0; k < NSL; ++k)
    atomicAdd(&P1[((size_t)b * NSL + k) * DIM + tid], acc[k]);
}

// ---------------------------------------------------------------- updates + GRU + LN + MLP + residual
// grid (64,2) x 192 threads; kg=0: slots 0..5, kg=1: slots 6..10.
__global__ __launch_bounds__(192) void k_gru(
    const float* __restrict__ P1, const float* __restrict__ m1g, const float* __restrict__ Sg,
    const float* __restrict__ xw, const float* __restrict__ xb,
    const float* __restrict__ Wv, const float* __restrict__ bv,
    const float* __restrict__ slots_in,
    const float* __restrict__ Wih, const float* __restrict__ Whh,
    const float* __restrict__ bih, const float* __restrict__ bhh,
    const float* __restrict__ lnw, const float* __restrict__ lnb,
    const float* __restrict__ W1, const float* __restrict__ b1,
    const float* __restrict__ W2, const float* __restrict__ b2,
    float* __restrict__ slots_ws, float* __restrict__ slots_out) {
  const int b = blockIdx.x, kg = blockIdx.y, tid = threadIdx.x;
  const int k0 = kg * 6, kcnt = kg ? 5 : 6;
  __shared__ __align__(16) float u[6][DIM];    // xa, then updates, then m=LN(h)
  __shared__ __align__(16) float hp[6][DIM];
  __shared__ __align__(16) float h[6][DIM];
  __shared__ __align__(16) float hid[6][HIDN];

  const int j = tid;
  const float wj = xw[j], bj = xb[j];
#pragma unroll
  for (int kk = 0; kk < 6; ++kk) {
    if (kk < kcnt) {
      int kidx = b * NSL + k0 + kk;
      float inv = 1.0f / Sg[kidx];
      u[kk][j]  = wj * (P1[(size_t)kidx * DIM + j] - m1g[kidx]) * inv + bj;
      hp[kk][j] = slots_in[(size_t)kidx * DIM + j];
    } else { u[kk][j] = 0.f; hp[kk][j] = 0.f; }
  }
  __syncthreads();

  // updates = xa @ Wv + bv
  float upd[6];
  const float bvj = bv[j];
#pragma unroll
  for (int kk = 0; kk < 6; ++kk) upd[kk] = bvj;
  for (int d = 0; d < DIM; d += 4) {
    float w0 = Wv[(d + 0) * DIM + j], w1 = Wv[(d + 1) * DIM + j];
    float w2 = Wv[(d + 2) * DIM + j], w3 = Wv[(d + 3) * DIM + j];
#pragma unroll
    for (int kk = 0; kk < 6; ++kk) {
      float4 x4 = *(const float4*)&u[kk][d];
      upd[kk] = fmaf(x4.w, w3, fmaf(x4.z, w2, fmaf(x4.y, w1, fmaf(x4.x, w0, upd[kk]))));
    }
  }
  __syncthreads();
#pragma unroll
  for (int kk = 0; kk < 6; ++kk) u[kk][j] = upd[kk];
  __syncthreads();

  // GRU
  float xr[6], xz[6], xn[6], hr[6], hz[6], hn[6];
  {
    float br_ = bih[j], bz_ = bih[DIM + j], bn_ = bih[2 * DIM + j];
    float cr_ = bhh[j], cz_ = bhh[DIM + j], cn_ = bhh[2 * DIM + j];
#pragma unroll
    for (int kk = 0; kk < 6; ++kk) { xr[kk] = br_; xz[kk] = bz_; xn[kk] = bn_; hr[kk] = cr_; hz[kk] = cz_; hn[kk] = cn_; }
  }
  const float* wr = Wih + (size_t)j * DIM;
  const float* wz = Wih + (size_t)(DIM + j) * DIM;
  const float* wn = Wih + (size_t)(2 * DIM + j) * DIM;
  const float* vr = Whh + (size_t)j * DIM;
  const float* vz = Whh + (size_t)(DIM + j) * DIM;
  const float* vn = Whh + (size_t)(2 * DIM + j) * DIM;

  for (int d = 0; d < DIM; d += 4) {
    float4 ar  = *(const float4*)(wr + d);
    float4 az  = *(const float4*)(wz + d);
    float4 an  = *(const float4*)(wn + d);
    float4 br4 = *(const float4*)(vr + d);
    float4 bz4 = *(const float4*)(vz + d);
    float4 bn4 = *(const float4*)(vn + d);
#pragma unroll
    for (int kk = 0; kk < 6; ++kk) {
      float4 u4 = *(const float4*)&u[kk][d];
      float4 p4 = *(const float4*)&hp[kk][d];
      xr[kk] = fmaf(u4.w, ar.w, fmaf(u4.z, ar.z, fmaf(u4.y, ar.y, fmaf(u4.x, ar.x, xr[kk]))));
      xz[kk] = fmaf(u4.w, az.w, fmaf(u4.z, az.z, fmaf(u4.y, az.y, fmaf(u4.x, az.x, xz[kk]))));
      xn[kk] = fmaf(u4.w, an.w, fmaf(u4.z, an.z, fmaf(u4.y, an.y, fmaf(u4.x, an.x, xn[kk]))));
      hr[kk] = fmaf(p4.w, br4.w, fmaf(p4.z, br4.z, fmaf(p4.y, br4.y, fmaf(p4.x, br4.x, hr[kk]))));
      hz[kk] = fmaf(p4.w, bz4.w, fmaf(p4.z, bz4.z, fmaf(p4.y, bz4.y, fmaf(p4.x, bz4.x, hz[kk]))));
      hn[kk] = fmaf(p4.w, bn4.w, fmaf(p4.z, bn4.z, fmaf(p4.y, bn4.y, fmaf(p4.x, bn4.x, hn[kk]))));
    }
  }

#pragma unroll
  for (int kk = 0; kk < 6; ++kk) {
    if (kk < kcnt) {
      float r = 1.f / (1.f + __expf(-(xr[kk] + hr[kk])));
      float z = 1.f / (1.f + __expf(-(xz[kk] + hz[kk])));
      float n = tanhf(xn[kk] + r * hn[kk]);
      h[kk][j] = (1.f - z) * n + z * hp[kk][j];
    }
  }
  __syncthreads();

  // LN(h) -> m (into u)
  const int wave = tid >> 6, lane = tid & 63;
  for (int kk = wave; kk < kcnt; kk += 3) {
    float a = h[kk][lane], c = h[kk][lane + 64], e = h[kk][lane + 128];
    float s = wred(a + c + e), ss = wred(a * a + c * c + e * e);
    float mu = s * (1.0f / DIM), var = ss * (1.0f / DIM) - mu * mu;
    float rstd = rsqrtf(var + LN_EPS);
    u[kk][lane]       = (a - mu) * rstd * lnw[lane]       + lnb[lane];
    u[kk][lane + 64]  = (c - mu) * rstd * lnw[lane + 64]  + lnb[lane + 64];
    u[kk][lane + 128] = (e - mu) * rstd * lnw[lane + 128] + lnb[lane + 128];
  }
  __syncthreads();

  for (int t = tid; t < kcnt * HIDN; t += 192) {
    int kk = t >> 7, c = t & (HIDN - 1);
    float acc = b1[c];
    for (int d = 0; d < DIM; d += 4) {
      float4 m4 = *(const float4*)&u[kk][d];
      acc = fmaf(m4.x, W1[(d + 0) * HIDN + c],
            fmaf(m4.y, W1[(d + 1) * HIDN + c],
            fmaf(m4.z, W1[(d + 2) * HIDN + c],
            fmaf(m4.w, W1[(d + 3) * HIDN + c], acc))));
    }
    hid[kk][c] = fmaxf(acc, 0.f);
  }
  __syncthreads();

  for (int kk = 0; kk < kcnt; ++kk) {
    float acc = b2[tid];
    for (int c = 0; c < HIDN; c += 4) {
      float4 h4 = *(const float4*)&hid[kk][c];
      acc = fmaf(h4.x, W2[(c + 0) * DIM + tid],
            fmaf(h4.y, W2[(c + 1) * DIM + tid],
            fmaf(h4.z, W2[(c + 2) * DIM + tid],
            fmaf(h4.w, W2[(c + 3) * DIM + tid], acc))));
    }
    float outv = h[kk][tid] + acc;
    size_t gi = (size_t)(b * NSL + k0 + kk) * DIM + tid;
    slots_ws[gi] = outv;
    slots_out[gi] = outv;
  }
}

// ---------------------------------------------------------------- launch
extern "C" void kernel_launch(void* const* d_in, const int* in_sizes, int n_in,
                              void* d_out, int out_size, void* d_ws, size_t ws_size,
                              hipStream_t stream) {
  const float* inputs      = (const float*)d_in[0];
  const float* noise       = (const float*)d_in[1];
  const float* slots_mu    = (const float*)d_in[2];
  const float* slots_sigma = (const float*)d_in[3];
  const float* ln_in_w     = (const float*)d_in[4];
  const float* ln_in_b     = (const float*)d_in[5];
  const float* ln_slots_w  = (const float*)d_in[6];
  const float* ln_slots_b  = (const float*)d_in[7];
  const float* ln_mlp_w    = (const float*)d_in[8];
  const float* ln_mlp_b    = (const float*)d_in[9];
  const float* Wq  = (const float*)d_in[10];
  const float* bq  = (const float*)d_in[11];
  const float* Wk  = (const float*)d_in[12];
  const float* bk  = (const float*)d_in[13];
  const float* Wv  = (const float*)d_in[14];
  const float* bv  = (const float*)d_in[15];
  const float* Wih = (const float*)d_in[16];
  const float* Whh = (const float*)d_in[17];
  const float* bih = (const float*)d_in[18];
  const float* bhh = (const float*)d_in[19];
  const float* W1  = (const float*)d_in[20];
  const float* b1  = (const float*)d_in[21];
  const float* W2  = (const float*)d_in[22];
  const float* b2  = (const float*)d_in[23];

  float* out = (float*)d_out;
  float* slots_out = out;                      // [64,11,192] fp32
  float* attn_out  = out + NB * NSL * DIM;     // [64,11,4096] fp32

  // workspace (3.56 MB total):
  char* w = (char*)d_ws;
  float2* stats = (float2*)w;                  //  2097152 B
  float* slots  = (float*)(w + 2097152);       //   540672 B
  float* qt     = (float*)(w + 2637824);       //   540672 B
  float* t0g    = (float*)(w + 3178496);       //     2816 B
  float* cpg    = (float*)(w + 3181312);       //     2816 B
  float* P1     = (float*)(w + 3184128);       //   540672 B
  float* m1g    = (float*)(w + 3724800);       //     2816 B
  float* Sg     = (float*)(w + 3727616);       //     2816 B  (P1+m1+S contiguous: 546304 B)

  k_init_slots<<<(NB * NSL * DIM + 255) / 256, 256, 0, stream>>>(noise, slots_mu, slots_sigma, slots);
  k_stats<<<(NB * NN) / 32, 256, 0, stream>>>(inputs, stats);

  for (int it = 0; it < 3; ++it) {
    hipMemsetAsync(P1, 0, 546304, stream);
    k_prep<<<NB, 192, 0, stream>>>(slots, ln_slots_w, ln_slots_b, Wq, bq, Wk, bk,
                                   ln_in_w, ln_in_b, qt, t0g, cpg);
    k_attn<<<dim3(NB, 8), 256, 0, stream>>>(inputs, stats, qt, t0g, cpg, attn_out, Sg, m1g);
    k_acc<<<dim3(NB, 8), 192, 0, stream>>>(attn_out, inputs, stats, P1);
    k_gru<<<dim3(NB, 2), 192, 0, stream>>>(P1, m1g, Sg, ln_in_w, ln_in_b, Wv, bv, slots,
                                           Wih, Whh, bih, bhh, ln_mlp_w, ln_mlp_b,
                                           W1, b1, W2, b2, slots, slots_out);
  }
}